// Round 13
// baseline (257.508 us; speedup 1.0000x reference)
//
#include <hip/hip_runtime.h>
#include <hip/hip_bf16.h>

#define HH 256
#define WW 832
#define OHH 128
#define OWW 208
#define NCAND 240
#define MM (OHH*OWW)

typedef float v2f __attribute__((ext_vector_type(2)));
typedef unsigned long long ull;

__device__ __forceinline__ int iclamp(int v, int lo, int hi) { return min(max(v, lo), hi); }
__device__ __forceinline__ int mbcnt2(ull m) {
    return __builtin_amdgcn_mbcnt_hi((unsigned)(m >> 32),
           __builtin_amdgcn_mbcnt_lo((unsigned)m, 0));
}
__device__ __forceinline__ v2f lo2(float4 f) { return (v2f){f.x, f.y}; }
__device__ __forceinline__ v2f hi2(float4 f) { return (v2f){f.z, f.w}; }

// DPP max-reduce step: v = max(v, dpp_shuffle(v)). VALU-only (no DS pipe).
template<int CTRL>
__device__ __forceinline__ float dppmax(float v) {
    int r = __builtin_amdgcn_update_dpp(__float_as_int(v), __float_as_int(v),
                                        CTRL, 0xF, 0xF, false);
    return fmaxf(v, __int_as_float(r));
}
// Max over each 32-lane half; valid in lanes 31 and 63.
__device__ __forceinline__ float halfmax32(float v) {
    v = dppmax<0x111>(v);   // row_shr:1
    v = dppmax<0x112>(v);   // row_shr:2
    v = dppmax<0x114>(v);   // row_shr:4
    v = dppmax<0x118>(v);   // row_shr:8
    v = dppmax<0x142>(v);   // row_bcast15
    return v;
}

// One wave = 4 consecutive centers (same output row). Rolled per-center loop:
// distance (lane-major, full-wave coalesced) -> radix walk -> scatter winners'
// rel-coords to LDS. Then two MLP+pool passes (lanes 0-31 / 32-63 = one
// center each). Minimizes wave count, per-wave prologue, code footprint, and
// removes the post-walk regather VMEM stall (rel-coords come from LDS).
__global__ void __launch_bounds__(256) sa_fused(
    const float* __restrict__ pos1, const float* __restrict__ pos2,
    const float* __restrict__ w1, const float* __restrict__ b1,
    const float* __restrict__ w2, const float* __restrict__ b2,
    const float* __restrict__ w3, const float* __restrict__ b3,
    float* __restrict__ out)
{
    __shared__ float4 sW1q[3][2];
    __shared__ float4 sW2q[8][2];
    __shared__ float4 sW3q[8][4];
    __shared__ float4 sB1q[2], sB2q[2], sB3q[4];
    __shared__ float4 selRel[512];   // 4 waves x 4 centers x 32 rel-coords

    const int t = threadIdx.x;
    if (t < 6)            { int i = t >> 1, qd = (t & 1) * 4;
        sW1q[i][t & 1] = make_float4(w1[i*8+qd], w1[i*8+qd+1], w1[i*8+qd+2], w1[i*8+qd+3]); }
    if (t >= 8 && t < 24) { int u = t - 8, i = u >> 1, qd = (u & 1) * 4;
        sW2q[i][u & 1] = make_float4(w2[i*8+qd], w2[i*8+qd+1], w2[i*8+qd+2], w2[i*8+qd+3]); }
    if (t >= 32 && t < 64){ int u = t - 32, i = u >> 2, qd = (u & 3) * 4;
        sW3q[i][u & 3] = make_float4(w3[i*16+qd], w3[i*16+qd+1], w3[i*16+qd+2], w3[i*16+qd+3]); }
    if (t >= 64 && t < 66){ int u = (t - 64) * 4; sB1q[t-64] = make_float4(b1[u], b1[u+1], b1[u+2], b1[u+3]); }
    if (t >= 66 && t < 68){ int u = (t - 66) * 4; sB2q[t-66] = make_float4(b2[u], b2[u+1], b2[u+2], b2[u+3]); }
    if (t >= 68 && t < 72){ int u = (t - 68) * 4; sB3q[t-68] = make_float4(b3[u], b3[u+1], b3[u+2], b3[u+3]); }
    __syncthreads();

    const int lane = t & 63;
    const int wid  = t >> 6;
    const int l31  = lane & 31;
    const int half = lane >> 5;
    const int mA   = blockIdx.x * 16 + wid * 4;   // centers mA..mA+3 (same row)
    const int b    = blockIdx.y & 1;
    const int cl   = blockIdx.y >> 1;
    const float* __restrict__ base = (cl ? pos2 : pos1) + (size_t)b * (HH * WW * 3);

    const int oh  = (int)(((unsigned)(mA >> 4) * 5042u) >> 16);  // mA/208, exact
    const int ow0 = mA - oh * OWW;
    const int h0  = oh * 2;
    const bool rowInt = ((unsigned)(oh - 3) <= 122u);

    // lane -> window cell (lane-major: j = 4*lane+q; kh const per lane)
    int kh  = (lane * 3277) >> 14;          // lane/5, exact for 0..63
    int kwb = (lane - kh * 5) * 4;
    if (lane >= 60) { kh = 11; kwb = 0; }   // tail: safe dummy cell (invalidated)

    #pragma unroll 1
    for (int cc = 0; cc < 4; ++cc) {
        const int ow = ow0 + cc;
        const int w0 = ow * 4;
        const float* cp = base + (h0 * WW + w0) * 3;
        const float cx = cp[0], cy = cp[1], cz = cp[2];

        unsigned d2b[4];
        float rxv[4], ryv[4], rzv[4];
        const bool interior = rowInt && ((unsigned)(ow - 3) <= 202u);
        if (interior) {
            // 12 contiguous floats; float-index ≡ 2 (mod 4) -> all naturally aligned
            const float* p = base + ((h0 - 6 + kh) * WW + (w0 - 10 + kwb)) * 3;
            float2 Av = *(const float2*)(p);
            float4 Bv = *(const float4*)(p + 2);
            float4 Cv = *(const float4*)(p + 6);
            float2 Dv = *(const float2*)(p + 10);
            float px[4] = {Av.x, Bv.y, Cv.x, Cv.w};
            float py[4] = {Av.y, Bv.z, Cv.y, Dv.x};
            float pz[4] = {Bv.x, Bv.w, Cv.z, Dv.y};
            #pragma unroll
            for (int q = 0; q < 4; ++q) {
                float dx = __fsub_rn(px[q], cx);
                float dy = __fsub_rn(py[q], cy);
                float dz = __fsub_rn(pz[q], cz);
                rxv[q] = dx; ryv[q] = dy; rzv[q] = dz;
                // match numpy f32 ordering exactly: (dx*dx + dy*dy) + dz*dz, no FMA
                d2b[q] = __float_as_uint(__fadd_rn(__fadd_rn(__fmul_rn(dx, dx), __fmul_rn(dy, dy)), __fmul_rn(dz, dz)));
            }
        } else {
            int chh = iclamp(h0 - 6 + kh, 0, HH - 1);
            #pragma unroll
            for (int q = 0; q < 4; ++q) {
                int cw = iclamp(w0 - 10 + kwb + q, 0, WW - 1);
                const float* p = base + (chh * WW + cw) * 3;
                float dx = __fsub_rn(p[0], cx);
                float dy = __fsub_rn(p[1], cy);
                float dz = __fsub_rn(p[2], cz);
                rxv[q] = dx; ryv[q] = dy; rzv[q] = dz;
                d2b[q] = __float_as_uint(__fadd_rn(__fadd_rn(__fmul_rn(dx, dx), __fmul_rn(dy, dy)), __fmul_rn(dz, dz)));
            }
        }
        if (lane >= 60) { d2b[0] = d2b[1] = d2b[2] = d2b[3] = 0xFFFFFFFFu; }

        // ---- radix-select the 32nd-smallest d2 (c0 = count(<T)) ----
        unsigned T = 0; int c0 = 0;
        for (int bpos = 30; bpos >= 0; --bpos) {
            unsigned Q = T | (1u << bpos);
            ull t0 = __ballot(d2b[0] < Q);
            ull t1 = __ballot(d2b[1] < Q);
            ull t2 = __ballot(d2b[2] < Q);
            ull t3 = __ballot(d2b[3] < Q);
            int c = __popcll(t0) + __popcll(t1) + __popcll(t2) + __popcll(t3);
            if (c == 32) { T = Q; c0 = 32; break; }   // {d2<T} is exactly the set
            if (c < 32)  { T = Q; c0 = c; }
        }

        // ---- winner masks (ties at T ranked in global candidate-index order) ----
        bool m0, m1, m2, m3;
        if (c0 == 32) {
            m0 = (d2b[0] < T); m1 = (d2b[1] < T); m2 = (d2b[2] < T); m3 = (d2b[3] < T);
        } else {
            const int r = 32 - c0;    // T == exact 32nd-smallest value
            bool eq0 = (d2b[0] == T), eq1 = (d2b[1] == T), eq2 = (d2b[2] == T), eq3 = (d2b[3] == T);
            ull e0 = __ballot(eq0), e1 = __ballot(eq1), e2 = __ballot(eq2), e3 = __ballot(eq3);
            int SA = mbcnt2(e0) + mbcnt2(e1) + mbcnt2(e2) + mbcnt2(e3);
            int E1 = (int)eq0, E2 = E1 + (int)eq1, E3 = E2 + (int)eq2;
            m0 = (d2b[0] < T) || (eq0 && (SA      < r));
            m1 = (d2b[1] < T) || (eq1 && (SA + E1 < r));
            m2 = (d2b[2] < T) || (eq2 && (SA + E2 < r));
            m3 = (d2b[3] < T) || (eq3 && (SA + E3 < r));
        }

        // ---- scatter winners' rel-coords to selRel[wid][cc][rank] ----
        ull s0 = __ballot(m0), s1 = __ballot(m1), s2 = __ballot(m2), s3 = __ballot(m3);
        int p1 = __popcll(s0), p2 = p1 + __popcll(s1), p3 = p2 + __popcll(s2);
        float4* lb = &selRel[wid * 128 + cc * 32];
        if (m0) lb[      mbcnt2(s0)] = make_float4(rxv[0], ryv[0], rzv[0], 0.f);
        if (m1) lb[p1 + mbcnt2(s1)] = make_float4(rxv[1], ryv[1], rzv[1], 0.f);
        if (m2) lb[p2 + mbcnt2(s2)] = make_float4(rxv[2], ryv[2], rzv[2], 0.f);
        if (m3) lb[p3 + mbcnt2(s3)] = make_float4(rxv[3], ryv[3], rzv[3], 0.f);
    }
    // same-wave LDS visibility: drain DS pipe, fence the scheduler
    asm volatile("s_waitcnt lgkmcnt(0)" ::: "memory");
    __builtin_amdgcn_sched_barrier(0);

    // ---- MLP passes: pass p handles centers mA+2p (lanes 0-31) / mA+2p+1 (32-63) ----
    #pragma unroll 1
    for (int p = 0; p < 2; ++p) {
        float4 rel = selRel[wid * 128 + (p * 2 + half) * 32 + l31];
        v2f rx2 = (v2f){rel.x, rel.x};
        v2f ry2 = (v2f){rel.y, rel.y};
        v2f rz2 = (v2f){rel.z, rel.z};

        v2f a1[4];
        {
            float4 bq0 = sB1q[0], bq1 = sB1q[1];
            float4 x0 = sW1q[0][0], x1 = sW1q[0][1];
            float4 y0 = sW1q[1][0], y1 = sW1q[1][1];
            float4 z0 = sW1q[2][0], z1 = sW1q[2][1];
            a1[0] = __builtin_elementwise_fma(rx2, lo2(x0), lo2(bq0));
            a1[1] = __builtin_elementwise_fma(rx2, hi2(x0), hi2(bq0));
            a1[2] = __builtin_elementwise_fma(rx2, lo2(x1), lo2(bq1));
            a1[3] = __builtin_elementwise_fma(rx2, hi2(x1), hi2(bq1));
            a1[0] = __builtin_elementwise_fma(ry2, lo2(y0), a1[0]);
            a1[1] = __builtin_elementwise_fma(ry2, hi2(y0), a1[1]);
            a1[2] = __builtin_elementwise_fma(ry2, lo2(y1), a1[2]);
            a1[3] = __builtin_elementwise_fma(ry2, hi2(y1), a1[3]);
            a1[0] = __builtin_elementwise_fma(rz2, lo2(z0), a1[0]);
            a1[1] = __builtin_elementwise_fma(rz2, hi2(z0), a1[1]);
            a1[2] = __builtin_elementwise_fma(rz2, lo2(z1), a1[2]);
            a1[3] = __builtin_elementwise_fma(rz2, hi2(z1), a1[3]);
            #pragma unroll
            for (int op = 0; op < 4; ++op) a1[op] = __builtin_elementwise_max(a1[op], (v2f)(0.f));
        }
        v2f a2[4] = {lo2(sB2q[0]), hi2(sB2q[0]), lo2(sB2q[1]), hi2(sB2q[1])};
        #pragma unroll
        for (int i = 0; i < 8; ++i) {
            float h = a1[i >> 1][i & 1];
            v2f hb = (v2f){h, h};
            float4 wl = sW2q[i][0], wh = sW2q[i][1];
            a2[0] = __builtin_elementwise_fma(hb, lo2(wl), a2[0]);
            a2[1] = __builtin_elementwise_fma(hb, hi2(wl), a2[1]);
            a2[2] = __builtin_elementwise_fma(hb, lo2(wh), a2[2]);
            a2[3] = __builtin_elementwise_fma(hb, hi2(wh), a2[3]);
        }
        #pragma unroll
        for (int op = 0; op < 4; ++op) a2[op] = __builtin_elementwise_max(a2[op], (v2f)(0.f));

        v2f a3[8] = {lo2(sB3q[0]), hi2(sB3q[0]), lo2(sB3q[1]), hi2(sB3q[1]),
                     lo2(sB3q[2]), hi2(sB3q[2]), lo2(sB3q[3]), hi2(sB3q[3])};
        #pragma unroll
        for (int i = 0; i < 8; ++i) {
            float h = a2[i >> 1][i & 1];
            v2f hb = (v2f){h, h};
            float4 q0 = sW3q[i][0], q1 = sW3q[i][1], q2 = sW3q[i][2], q3 = sW3q[i][3];
            a3[0] = __builtin_elementwise_fma(hb, lo2(q0), a3[0]);
            a3[1] = __builtin_elementwise_fma(hb, hi2(q0), a3[1]);
            a3[2] = __builtin_elementwise_fma(hb, lo2(q1), a3[2]);
            a3[3] = __builtin_elementwise_fma(hb, hi2(q1), a3[3]);
            a3[4] = __builtin_elementwise_fma(hb, lo2(q2), a3[4]);
            a3[5] = __builtin_elementwise_fma(hb, hi2(q2), a3[5]);
            a3[6] = __builtin_elementwise_fma(hb, lo2(q3), a3[6]);
            a3[7] = __builtin_elementwise_fma(hb, hi2(q3), a3[7]);
        }

        // DPP max-pool over each 32-lane half; valid in lanes 31/63.
        float hv[16];
        #pragma unroll
        for (int op = 0; op < 8; ++op) { hv[2*op] = a3[op].x; hv[2*op+1] = a3[op].y; }
        #pragma unroll
        for (int o = 0; o < 16; ++o) hv[o] = halfmax32(hv[o]);
        if (l31 == 31) {
            #pragma unroll
            for (int o = 0; o < 16; ++o) hv[o] = fmaxf(hv[o], 0.f);  // relu after pool
            const int ms = mA + p * 2 + half;
            float4* dst = (float4*)(out + ((size_t)(b * MM + ms) * 32) + (size_t)cl * 16);
            dst[0] = make_float4(hv[0],  hv[1],  hv[2],  hv[3]);
            dst[1] = make_float4(hv[4],  hv[5],  hv[6],  hv[7]);
            dst[2] = make_float4(hv[8],  hv[9],  hv[10], hv[11]);
            dst[3] = make_float4(hv[12], hv[13], hv[14], hv[15]);
        }
    }
}

extern "C" void kernel_launch(void* const* d_in, const int* in_sizes, int n_in,
                              void* d_out, int out_size, void* d_ws, size_t ws_size,
                              hipStream_t stream) {
    const float* pos1 = (const float*)d_in[0];
    const float* pos2 = (const float*)d_in[1];
    const float* w1   = (const float*)d_in[2];
    const float* b1   = (const float*)d_in[3];
    const float* w2   = (const float*)d_in[4];
    const float* b2   = (const float*)d_in[5];
    const float* w3   = (const float*)d_in[6];
    const float* b3   = (const float*)d_in[7];
    float* out = (float*)d_out;

    dim3 grid(MM / 16, 4);   // 1664 blocks x {batch, cloud}; 4 centers/wave
    sa_fused<<<grid, 256, 0, stream>>>(pos1, pos2, w1, b1, w2, b2, w3, b3, out);
}

// Round 14
// 88.863 us; speedup vs baseline: 2.8978x; 2.8978x over previous
//
#include <hip/hip_runtime.h>
#include <hip/hip_bf16.h>

#define HH 256
#define WW 832
#define OHH 128
#define OWW 208
#define NCAND 240
#define MM (OHH*OWW)

typedef float v2f __attribute__((ext_vector_type(2)));
typedef unsigned long long ull;

__device__ __forceinline__ int iclamp(int v, int lo, int hi) { return min(max(v, lo), hi); }
__device__ __forceinline__ int mbcnt2(ull m) {
    return __builtin_amdgcn_mbcnt_hi((unsigned)(m >> 32),
           __builtin_amdgcn_mbcnt_lo((unsigned)m, 0));
}
__device__ __forceinline__ v2f lo2(float4 f) { return (v2f){f.x, f.y}; }
__device__ __forceinline__ v2f hi2(float4 f) { return (v2f){f.z, f.w}; }

// DPP max-reduce step: v = max(v, dpp_shuffle(v)). VALU-only (no DS pipe).
template<int CTRL>
__device__ __forceinline__ float dppmax(float v) {
    int r = __builtin_amdgcn_update_dpp(__float_as_int(v), __float_as_int(v),
                                        CTRL, 0xF, 0xF, false);
    return fmaxf(v, __int_as_float(r));
}
// Max over each 32-lane half; valid in lanes 31 and 63.
__device__ __forceinline__ float halfmax32(float v) {
    v = dppmax<0x111>(v);   // row_shr:1
    v = dppmax<0x112>(v);   // row_shr:2
    v = dppmax<0x114>(v);   // row_shr:4
    v = dppmax<0x118>(v);   // row_shr:8
    v = dppmax<0x142>(v);   // row_bcast15
    return v;
}

// R9 structure (best known): one wave = 2 consecutive centers, both distance
// passes fully unrolled, ONE fused radix walk with independent latched
// states. Consolidated micro-opts: winners' rel-coords scatter to LDS as
// float4 (no MLP regather), DPP max-pool (no DS-pipe butterfly).
// NOTE (R13 lesson): keep all per-center loops fully unrolled — a rolled
// center loop makes the compiler hold 4x state live -> 144 VGPR, 11% occ.
__global__ void __launch_bounds__(256) sa_fused(
    const float* __restrict__ pos1, const float* __restrict__ pos2,
    const float* __restrict__ w1, const float* __restrict__ b1,
    const float* __restrict__ w2, const float* __restrict__ b2,
    const float* __restrict__ w3, const float* __restrict__ b3,
    float* __restrict__ out)
{
    __shared__ float4 sW1q[3][2];
    __shared__ float4 sW2q[8][2];
    __shared__ float4 sW3q[8][4];
    __shared__ float4 sB1q[2], sB2q[2], sB3q[4];
    __shared__ float4 selRel[256];   // 4 waves x 2 centers x 32 rel-coords

    const int t = threadIdx.x;
    if (t < 6)            { int i = t >> 1, qd = (t & 1) * 4;
        sW1q[i][t & 1] = make_float4(w1[i*8+qd], w1[i*8+qd+1], w1[i*8+qd+2], w1[i*8+qd+3]); }
    if (t >= 8 && t < 24) { int u = t - 8, i = u >> 1, qd = (u & 1) * 4;
        sW2q[i][u & 1] = make_float4(w2[i*8+qd], w2[i*8+qd+1], w2[i*8+qd+2], w2[i*8+qd+3]); }
    if (t >= 32 && t < 64){ int u = t - 32, i = u >> 2, qd = (u & 3) * 4;
        sW3q[i][u & 3] = make_float4(w3[i*16+qd], w3[i*16+qd+1], w3[i*16+qd+2], w3[i*16+qd+3]); }
    if (t >= 64 && t < 66){ int u = (t - 64) * 4; sB1q[t-64] = make_float4(b1[u], b1[u+1], b1[u+2], b1[u+3]); }
    if (t >= 66 && t < 68){ int u = (t - 66) * 4; sB2q[t-66] = make_float4(b2[u], b2[u+1], b2[u+2], b2[u+3]); }
    if (t >= 68 && t < 72){ int u = (t - 68) * 4; sB3q[t-68] = make_float4(b3[u], b3[u+1], b3[u+2], b3[u+3]); }
    __syncthreads();

    const int lane = t & 63;
    const int wid  = t >> 6;
    const int l31  = lane & 31;
    const int half = lane >> 5;
    const int mA   = blockIdx.x * 8 + wid * 2;   // centers mA, mA+1
    const int b    = blockIdx.y & 1;
    const int cl   = blockIdx.y >> 1;
    const float* __restrict__ base = (cl ? pos2 : pos1) + (size_t)b * (HH * WW * 3);

    // lane -> window cell (lane-major: j = 4*lane+q; kh const per lane)
    int kh  = (lane * 3277) >> 14;          // lane/5, exact for 0..63
    int kwb = (lane - kh * 5) * 4;
    if (lane >= 60) { kh = 11; kwb = 0; }   // tail: safe dummy cell (invalidated)

    unsigned dA0, dA1, dA2, dA3, dB0, dB1, dB2, dB3;
    float rAx[4], rAy[4], rAz[4], rBx[4], rBy[4], rBz[4];

    auto distpass = [&](int m, unsigned& D0, unsigned& D1, unsigned& D2, unsigned& D3,
                        float* RX, float* RY, float* RZ) {
        const int oh = (int)(((unsigned)(m >> 4) * 5042u) >> 16);  // m/208, exact
        const int ow = m - oh * OWW;
        const int h0 = oh * 2, w0 = ow * 4;
        const float cx = base[(h0 * WW + w0) * 3 + 0];
        const float cy = base[(h0 * WW + w0) * 3 + 1];
        const float cz = base[(h0 * WW + w0) * 3 + 2];
        unsigned d2b[4];
        const bool interior = ((unsigned)(oh - 3) <= 122u) && ((unsigned)(ow - 3) <= 202u);
        if (interior) {
            // 12 contiguous floats; float-index ≡ 2 (mod 4) -> all naturally aligned
            const float* p = base + ((h0 - 6 + kh) * WW + (w0 - 10 + kwb)) * 3;
            float2 Av = *(const float2*)(p);
            float4 Bv = *(const float4*)(p + 2);
            float4 Cv = *(const float4*)(p + 6);
            float2 Dv = *(const float2*)(p + 10);
            float px[4] = {Av.x, Bv.y, Cv.x, Cv.w};
            float py[4] = {Av.y, Bv.z, Cv.y, Dv.x};
            float pz[4] = {Bv.x, Bv.w, Cv.z, Dv.y};
            #pragma unroll
            for (int q = 0; q < 4; ++q) {
                float dx = __fsub_rn(px[q], cx);
                float dy = __fsub_rn(py[q], cy);
                float dz = __fsub_rn(pz[q], cz);
                RX[q] = dx; RY[q] = dy; RZ[q] = dz;
                // match numpy f32 ordering exactly: (dx*dx + dy*dy) + dz*dz, no FMA
                d2b[q] = __float_as_uint(__fadd_rn(__fadd_rn(__fmul_rn(dx, dx), __fmul_rn(dy, dy)), __fmul_rn(dz, dz)));
            }
        } else {
            int chh = iclamp(h0 - 6 + kh, 0, HH - 1);
            #pragma unroll
            for (int q = 0; q < 4; ++q) {
                int cw = iclamp(w0 - 10 + kwb + q, 0, WW - 1);
                const float* p = base + (chh * WW + cw) * 3;
                float dx = __fsub_rn(p[0], cx);
                float dy = __fsub_rn(p[1], cy);
                float dz = __fsub_rn(p[2], cz);
                RX[q] = dx; RY[q] = dy; RZ[q] = dz;
                d2b[q] = __float_as_uint(__fadd_rn(__fadd_rn(__fmul_rn(dx, dx), __fmul_rn(dy, dy)), __fmul_rn(dz, dz)));
            }
        }
        if (lane >= 60) { d2b[0] = d2b[1] = d2b[2] = d2b[3] = 0xFFFFFFFFu; }
        D0 = d2b[0]; D1 = d2b[1]; D2 = d2b[2]; D3 = d2b[3];
    };
    distpass(mA,     dA0, dA1, dA2, dA3, rAx, rAy, rAz);
    distpass(mA + 1, dB0, dB1, dB2, dB3, rBx, rBy, rBz);

    // ---- fused radix walks: two independent serial chains, interleaved ----
    unsigned TA = 0, TB = 0; int c0A = 0, c0B = 0;
    bool exactA = false, exactB = false;
    for (int bpos = 30; bpos >= 0; --bpos) {
        if (!exactA) {
            unsigned Q = TA | (1u << bpos);
            ull t0 = __ballot(dA0 < Q);
            ull t1 = __ballot(dA1 < Q);
            ull t2 = __ballot(dA2 < Q);
            ull t3 = __ballot(dA3 < Q);
            int c = __popcll(t0) + __popcll(t1) + __popcll(t2) + __popcll(t3);
            if (c == 32) { TA = Q; c0A = 32; exactA = true; }
            else if (c < 32) { TA = Q; c0A = c; }
        }
        if (!exactB) {
            unsigned Q = TB | (1u << bpos);
            ull t0 = __ballot(dB0 < Q);
            ull t1 = __ballot(dB1 < Q);
            ull t2 = __ballot(dB2 < Q);
            ull t3 = __ballot(dB3 < Q);
            int c = __popcll(t0) + __popcll(t1) + __popcll(t2) + __popcll(t3);
            if (c == 32) { TB = Q; c0B = 32; exactB = true; }
            else if (c < 32) { TB = Q; c0B = c; }
        }
        if (exactA && exactB) break;
    }

    // ---- winner masks + scatter rel-coords; center A -> slots 0-31 ----
    {
        bool m0, m1, m2, m3;
        if (c0A == 32) {
            m0 = (dA0 < TA); m1 = (dA1 < TA); m2 = (dA2 < TA); m3 = (dA3 < TA);
        } else {
            const int r = 32 - c0A;   // TA == exact 32nd value; ties in global j order
            bool eq0 = (dA0 == TA), eq1 = (dA1 == TA), eq2 = (dA2 == TA), eq3 = (dA3 == TA);
            ull e0 = __ballot(eq0), e1 = __ballot(eq1), e2 = __ballot(eq2), e3 = __ballot(eq3);
            int SA = mbcnt2(e0) + mbcnt2(e1) + mbcnt2(e2) + mbcnt2(e3);
            int E1 = (int)eq0, E2 = E1 + (int)eq1, E3 = E2 + (int)eq2;
            m0 = (dA0 < TA) || (eq0 && (SA      < r));
            m1 = (dA1 < TA) || (eq1 && (SA + E1 < r));
            m2 = (dA2 < TA) || (eq2 && (SA + E2 < r));
            m3 = (dA3 < TA) || (eq3 && (SA + E3 < r));
        }
        ull s0 = __ballot(m0), s1 = __ballot(m1), s2 = __ballot(m2), s3 = __ballot(m3);
        int p1 = __popcll(s0), p2 = p1 + __popcll(s1), p3 = p2 + __popcll(s2);
        float4* lb = &selRel[wid * 64];
        if (m0) lb[     mbcnt2(s0)] = make_float4(rAx[0], rAy[0], rAz[0], 0.f);
        if (m1) lb[p1 + mbcnt2(s1)] = make_float4(rAx[1], rAy[1], rAz[1], 0.f);
        if (m2) lb[p2 + mbcnt2(s2)] = make_float4(rAx[2], rAy[2], rAz[2], 0.f);
        if (m3) lb[p3 + mbcnt2(s3)] = make_float4(rAx[3], rAy[3], rAz[3], 0.f);
    }
    {   // center B -> slots 32-63
        bool m0, m1, m2, m3;
        if (c0B == 32) {
            m0 = (dB0 < TB); m1 = (dB1 < TB); m2 = (dB2 < TB); m3 = (dB3 < TB);
        } else {
            const int r = 32 - c0B;
            bool eq0 = (dB0 == TB), eq1 = (dB1 == TB), eq2 = (dB2 == TB), eq3 = (dB3 == TB);
            ull e0 = __ballot(eq0), e1 = __ballot(eq1), e2 = __ballot(eq2), e3 = __ballot(eq3);
            int SA = mbcnt2(e0) + mbcnt2(e1) + mbcnt2(e2) + mbcnt2(e3);
            int E1 = (int)eq0, E2 = E1 + (int)eq1, E3 = E2 + (int)eq2;
            m0 = (dB0 < TB) || (eq0 && (SA      < r));
            m1 = (dB1 < TB) || (eq1 && (SA + E1 < r));
            m2 = (dB2 < TB) || (eq2 && (SA + E2 < r));
            m3 = (dB3 < TB) || (eq3 && (SA + E3 < r));
        }
        ull s0 = __ballot(m0), s1 = __ballot(m1), s2 = __ballot(m2), s3 = __ballot(m3);
        int p1 = __popcll(s0), p2 = p1 + __popcll(s1), p3 = p2 + __popcll(s2);
        float4* lb = &selRel[wid * 64 + 32];
        if (m0) lb[     mbcnt2(s0)] = make_float4(rBx[0], rBy[0], rBz[0], 0.f);
        if (m1) lb[p1 + mbcnt2(s1)] = make_float4(rBx[1], rBy[1], rBz[1], 0.f);
        if (m2) lb[p2 + mbcnt2(s2)] = make_float4(rBx[2], rBy[2], rBz[2], 0.f);
        if (m3) lb[p3 + mbcnt2(s3)] = make_float4(rBx[3], rBy[3], rBz[3], 0.f);
    }
    // same-wave LDS visibility: drain DS pipe, fence the scheduler
    asm volatile("s_waitcnt lgkmcnt(0)" ::: "memory");
    __builtin_amdgcn_sched_barrier(0);

    // ---- MLP: lane = half*32 + n -> neighbor n of center mA+half; all 16 ch ----
    {
        float4 rel = selRel[wid * 64 + lane];
        v2f rx2 = (v2f){rel.x, rel.x};
        v2f ry2 = (v2f){rel.y, rel.y};
        v2f rz2 = (v2f){rel.z, rel.z};

        v2f a1[4];
        {
            float4 bq0 = sB1q[0], bq1 = sB1q[1];
            float4 x0 = sW1q[0][0], x1 = sW1q[0][1];
            float4 y0 = sW1q[1][0], y1 = sW1q[1][1];
            float4 z0 = sW1q[2][0], z1 = sW1q[2][1];
            a1[0] = __builtin_elementwise_fma(rx2, lo2(x0), lo2(bq0));
            a1[1] = __builtin_elementwise_fma(rx2, hi2(x0), hi2(bq0));
            a1[2] = __builtin_elementwise_fma(rx2, lo2(x1), lo2(bq1));
            a1[3] = __builtin_elementwise_fma(rx2, hi2(x1), hi2(bq1));
            a1[0] = __builtin_elementwise_fma(ry2, lo2(y0), a1[0]);
            a1[1] = __builtin_elementwise_fma(ry2, hi2(y0), a1[1]);
            a1[2] = __builtin_elementwise_fma(ry2, lo2(y1), a1[2]);
            a1[3] = __builtin_elementwise_fma(ry2, hi2(y1), a1[3]);
            a1[0] = __builtin_elementwise_fma(rz2, lo2(z0), a1[0]);
            a1[1] = __builtin_elementwise_fma(rz2, hi2(z0), a1[1]);
            a1[2] = __builtin_elementwise_fma(rz2, lo2(z1), a1[2]);
            a1[3] = __builtin_elementwise_fma(rz2, hi2(z1), a1[3]);
            #pragma unroll
            for (int op = 0; op < 4; ++op) a1[op] = __builtin_elementwise_max(a1[op], (v2f)(0.f));
        }
        v2f a2[4] = {lo2(sB2q[0]), hi2(sB2q[0]), lo2(sB2q[1]), hi2(sB2q[1])};
        #pragma unroll
        for (int i = 0; i < 8; ++i) {
            float h = a1[i >> 1][i & 1];
            v2f hb = (v2f){h, h};
            float4 wl = sW2q[i][0], wh = sW2q[i][1];
            a2[0] = __builtin_elementwise_fma(hb, lo2(wl), a2[0]);
            a2[1] = __builtin_elementwise_fma(hb, hi2(wl), a2[1]);
            a2[2] = __builtin_elementwise_fma(hb, lo2(wh), a2[2]);
            a2[3] = __builtin_elementwise_fma(hb, hi2(wh), a2[3]);
        }
        #pragma unroll
        for (int op = 0; op < 4; ++op) a2[op] = __builtin_elementwise_max(a2[op], (v2f)(0.f));

        v2f a3[8] = {lo2(sB3q[0]), hi2(sB3q[0]), lo2(sB3q[1]), hi2(sB3q[1]),
                     lo2(sB3q[2]), hi2(sB3q[2]), lo2(sB3q[3]), hi2(sB3q[3])};
        #pragma unroll
        for (int i = 0; i < 8; ++i) {
            float h = a2[i >> 1][i & 1];
            v2f hb = (v2f){h, h};
            float4 q0 = sW3q[i][0], q1 = sW3q[i][1], q2 = sW3q[i][2], q3 = sW3q[i][3];
            a3[0] = __builtin_elementwise_fma(hb, lo2(q0), a3[0]);
            a3[1] = __builtin_elementwise_fma(hb, hi2(q0), a3[1]);
            a3[2] = __builtin_elementwise_fma(hb, lo2(q1), a3[2]);
            a3[3] = __builtin_elementwise_fma(hb, hi2(q1), a3[3]);
            a3[4] = __builtin_elementwise_fma(hb, lo2(q2), a3[4]);
            a3[5] = __builtin_elementwise_fma(hb, hi2(q2), a3[5]);
            a3[6] = __builtin_elementwise_fma(hb, lo2(q3), a3[6]);
            a3[7] = __builtin_elementwise_fma(hb, hi2(q3), a3[7]);
        }

        // DPP max-pool over each 32-lane half (VALU-only); valid in lanes 31/63.
        float hv[16];
        #pragma unroll
        for (int op = 0; op < 8; ++op) { hv[2*op] = a3[op].x; hv[2*op+1] = a3[op].y; }
        #pragma unroll
        for (int o = 0; o < 16; ++o) hv[o] = halfmax32(hv[o]);
        if (l31 == 31) {
            #pragma unroll
            for (int o = 0; o < 16; ++o) hv[o] = fmaxf(hv[o], 0.f);  // relu after pool
            const int ms = mA + half;
            float4* dst = (float4*)(out + ((size_t)(b * MM + ms) * 32) + (size_t)cl * 16);
            dst[0] = make_float4(hv[0],  hv[1],  hv[2],  hv[3]);
            dst[1] = make_float4(hv[4],  hv[5],  hv[6],  hv[7]);
            dst[2] = make_float4(hv[8],  hv[9],  hv[10], hv[11]);
            dst[3] = make_float4(hv[12], hv[13], hv[14], hv[15]);
        }
    }
}

extern "C" void kernel_launch(void* const* d_in, const int* in_sizes, int n_in,
                              void* d_out, int out_size, void* d_ws, size_t ws_size,
                              hipStream_t stream) {
    const float* pos1 = (const float*)d_in[0];
    const float* pos2 = (const float*)d_in[1];
    const float* w1   = (const float*)d_in[2];
    const float* b1   = (const float*)d_in[3];
    const float* w2   = (const float*)d_in[4];
    const float* b2   = (const float*)d_in[5];
    const float* w3   = (const float*)d_in[6];
    const float* b3   = (const float*)d_in[7];
    float* out = (float*)d_out;

    dim3 grid(MM / 8, 4);   // 3328 blocks x {batch, cloud}; 2 centers/wave
    sa_fused<<<grid, 256, 0, stream>>>(pos1, pos2, w1, b1, w2, b2, w3, b3, out);
}